// Round 1
// baseline (3246.132 us; speedup 1.0000x reference)
//
#include <hip/hip_runtime.h>
#include <hip/hip_fp16.h>
#include <cstdint>
#include <cstddef>

#define T_STEPS 256
#define K_DIM 2048
#define ROWS 64          // rows per pair (pair = 2 blocks splitting K columns)
#define NWAVES 8
#define NT_W 8           // ntiles (16 cols) per wave: 128 cols/wave, 1024/block
#define REG_NT 4         // ntiles per wave in VGPRs/AGPRs
#define LDS_NT 4         // ntiles per wave in LDS (128 KB)

typedef _Float16 f16;
typedef _Float16 f16x8 __attribute__((ext_vector_type(8)));
typedef _Float16 f16x4 __attribute__((ext_vector_type(4)));
typedef float f32x4 __attribute__((ext_vector_type(4)));

// LDS layout (static so the compiler sees true occupancy: 1 block/CU)
#define W1S_OFF 0        // 8 waves * 4 nt * 4 ks * 64 lanes * 16B = 131072
#define U_OFF   131072   // u region [64 rows][64 cols] f16 swizzled = 8192
#define Y_OFF   139264   // y regions [2][64 rows][64 cols] f16 swizzled = 16384
#define PB_OFF  155648   // predbuf f32[8][64] = 2048
#define PF_OFF  157696   // predf16 f16[64] = 128
#define FLAG_OFF 157824  // unsigned step tag
#define SMEM_BYTES 157840

// workspace layout
#define W1P_BYTES (128 * 4 * 64 * 16)            // 524288: packed fp16 W1
#define MBOX_OFF  W1P_BYTES                      // u64[256][2][64] = 262144
#define MBOX_BYTES (256 * 2 * 64 * 8)

// Pack W1 [128][2048] f32 row-major into fp16 MFMA-B-fragment layout:
// w1p[((ntile*4 + ks)*64 + lane)*8 + i] = W1[ks*32 + (lane>>4)*8 + i][ntile*16 + (lane&15)]
__global__ void __launch_bounds__(64) prepack_w1(const float* __restrict__ W1,
                                                 f16* __restrict__ w1p) {
  int blk = blockIdx.x;            // 0..511 = ntile*4 + ks
  int ntile = blk >> 2, ks = blk & 3;
  int lane = threadIdx.x;
  int col = ntile * 16 + (lane & 15);
  int kb = ks * 32 + ((lane >> 4) << 3);
  f16x8 pk;
#pragma unroll
  for (int i = 0; i < 8; ++i) pk[i] = (f16)W1[(size_t)(kb + i) * K_DIM + col];
  ((f16x8*)w1p)[(ntile * 4 + ks) * 64 + lane] = pk;
}

__global__ void __launch_bounds__(512, 2)
__attribute__((amdgpu_waves_per_eu(2, 2)))
rnn_fused(
    const float* __restrict__ u, const float* __restrict__ y0,
    const f16* __restrict__ w1p, const float* __restrict__ W1f,
    const float* __restrict__ b1, const float* __restrict__ w2,
    const float* __restrict__ b2, float* __restrict__ out,
    unsigned long long* mbox)
{
  __shared__ __align__(16) char smem[SMEM_BYTES];
  f16x8* w1s     = (f16x8*)(smem + W1S_OFF);
  float* predbuf = (float*)(smem + PB_OFF);
  f16*   predf16 = (f16*)(smem + PF_OFF);
  unsigned* flagw = (unsigned*)(smem + FLAG_OFF);

  const int tid = threadIdx.x, lane = tid & 63, wave = tid >> 6;
  const int b = blockIdx.x;
  const int jj_ = b >> 3;
  const int half = jj_ & 1;                 // which K-half of W1
  const int pair = ((b & 7) << 4) | (jj_ >> 1);
  const int partner = b ^ 8;
  const int row0 = pair * ROWS;
  const int colbase = half * 1024;
  const float b2v = b2[0];
  const f16x8* w1pv = (const f16x8*)w1p;
  const float TWO_L = 2.885390081777927f;   // 2*log2(e)

  // per-lane epilogue constants.  w164L = TWO_L * W1[row 64][col]:
  // X col 64 (the freshest pred) is kept ZERO in LDS; its contribution is a
  // rank-1 correction applied in the epilogue, so the pair exchange is OFF
  // the GEMM critical path.
  float b1x[NT_W], w2v[NT_W], w164L[NT_W];
#pragma unroll
  for (int nt = 0; nt < NT_W; ++nt) {
    int col = colbase + wave * 128 + nt * 16 + (lane & 15);
    b1x[nt]   = TWO_L * b1[col];
    w2v[nt]   = w2[col];
    w164L[nt] = TWO_L * W1f[(size_t)64 * K_DIM + col];
  }

  // C_half = sum of w2 over this block's 1024 cols (register-resident, wave 0)
  float Chalf = 0.f;
  if (wave == 0) {
    float s = 0.f;
#pragma unroll
    for (int i = 0; i < 16; ++i) s += w2[colbase + lane * 16 + i];
    s += __shfl_xor(s, 1);  s += __shfl_xor(s, 2);  s += __shfl_xor(s, 4);
    s += __shfl_xor(s, 8);  s += __shfl_xor(s, 16); s += __shfl_xor(s, 32);
    Chalf = s;
  }

  // W1: REG_NT ntiles/wave in regs, LDS_NT ntiles/wave in LDS.
  f16x8 w1r[REG_NT * 4];
#pragma unroll
  for (int nt = 0; nt < REG_NT; ++nt)
#pragma unroll
    for (int ks = 0; ks < 4; ++ks)
      w1r[nt * 4 + ks] = w1pv[((half * 64 + wave * 8 + nt) * 4 + ks) * 64 + lane];
#pragma unroll
  for (int i = 0; i < REG_NT * 4; ++i) asm volatile("" : "+v"(w1r[i]));

#pragma unroll
  for (int nt = 0; nt < LDS_NT; ++nt)
#pragma unroll
    for (int ks = 0; ks < 4; ++ks)
      w1s[((wave * LDS_NT + nt) * 4 + ks) * 64 + lane] =
          w1pv[((half * 64 + wave * 8 + REG_NT + nt) * 4 + ks) * 64 + lane];

  if (tid == 0) *flagw = 0u;   // step-0 correction value is pre-published

  // y0 -> y[0]; y-region col 0 (= X col 64) deferred: store 0, value to predf16
  {
    int r = tid >> 3, j0 = (tid & 7) * 8;
    const float4* yp = (const float4*)(y0 + (size_t)(row0 + r) * 64 + j0);
    float4 a = yp[0], c = yp[1];
    f16x8 pk;
    pk[0] = (f16)a.x; pk[1] = (f16)a.y; pk[2] = (f16)a.z; pk[3] = (f16)a.w;
    pk[4] = (f16)c.x; pk[5] = (f16)c.y; pk[6] = (f16)c.z; pk[7] = (f16)c.w;
    if (j0 == 0) { pk[0] = (f16)0.f; predf16[r] = (f16)a.x; }
    int byte = (r * 128 + j0 * 2) ^ ((r & 7) << 4);
    *(f16x8*)(smem + Y_OFF + byte) = pk;
  }
  // u_0 -> u region, then prefetch u_1 into regs
  {
    int r = tid >> 3, j0 = (tid & 7) * 8;
    const float4* p = (const float4*)(u + ((size_t)(row0 + r) * T_STEPS + 0) * 64 + j0);
    float4 a = p[0], c = p[1];
    f16x8 pk;
    pk[0] = (f16)a.x; pk[1] = (f16)a.y; pk[2] = (f16)a.z; pk[3] = (f16)a.w;
    pk[4] = (f16)c.x; pk[5] = (f16)c.y; pk[6] = (f16)c.z; pk[7] = (f16)c.w;
    int byte = (r * 128 + j0 * 2) ^ ((r & 7) << 4);
    *(f16x8*)(smem + U_OFF + byte) = pk;
  }
  float4 up0, up1;
  {
    int r = tid >> 3, j0 = (tid & 7) * 8;
    const float4* p = (const float4*)(u + ((size_t)(row0 + r) * T_STEPS + 1) * 64 + j0);
    up0 = p[0]; up1 = p[1];
  }
  __syncthreads();  // X valid for t=0

  float contrib = 0.f;   // wave0: this block's half-sum from previous step

  for (int t = 0; t < T_STEPS; ++t) {
    const int par = t & 1;

    // ---- wave 0: finalize pred_{t-1} (posted by both blocks at end of t-1),
    //      publish to LDS + flag.  Other waves start the GEMM meanwhile. ----
    if (wave == 0 && t > 0) {
      const unsigned want = (unsigned)t;
      unsigned long long pv;
      do {
        pv = __hip_atomic_load(&mbox[((size_t)(partner * 2 + ((t - 1) & 1))) * 64 + lane],
                               __ATOMIC_RELAXED, __HIP_MEMORY_SCOPE_AGENT);
      } while ((unsigned)(pv >> 32) != want);
      float pc = __builtin_bit_cast(float, (unsigned)(pv & 0xffffffffu));
      float ps = contrib + pc + b2v;
      if (half == 0) out[(size_t)(row0 + lane) * T_STEPS + (t - 1)] = ps;
      predf16[lane] = (f16)ps;
      __hip_atomic_store(flagw, (unsigned)t, __ATOMIC_RELEASE, __HIP_MEMORY_SCOPE_WORKGROUP);
    }

    // ---- A-fragments for 64 rows (u region + y[par] region) ----
    f16x8 af[4][4];
    {
      const char* ubase = smem + U_OFF;
      const char* ybase = smem + Y_OFF + par * 8192;
      int koff2 = ((lane >> 4) << 4);      // byte offset of this lane's 8-f16 chunk
#pragma unroll
      for (int mt = 0; mt < 4; ++mt) {
        int r = mt * 16 + (lane & 15);
        int base = r * 128 + koff2;
        int sw = (r & 7) << 4;
        af[mt][0] = *(const f16x8*)(ubase + ((base) ^ sw));
        af[mt][1] = *(const f16x8*)(ubase + ((base + 64) ^ sw));
        af[mt][2] = *(const f16x8*)(ybase + ((base) ^ sw));
        af[mt][3] = *(const f16x8*)(ybase + ((base + 64) ^ sw));
      }
    }

    auto mfma_nt = [&](int nt, f32x4* acc) {
#pragma unroll
      for (int mt = 0; mt < 4; ++mt) acc[mt] = (f32x4){0.f, 0.f, 0.f, 0.f};
#pragma unroll
      for (int ks = 0; ks < 4; ++ks) {
        f16x8 bf = (nt < REG_NT)
                       ? w1r[nt * 4 + ks]
                       : w1s[((wave * LDS_NT + (nt - REG_NT)) * 4 + ks) * 64 + lane];
#pragma unroll
        for (int mt = 0; mt < 4; ++mt)
          acc[mt] = __builtin_amdgcn_mfma_f32_16x16x32_f16(af[mt][ks], bf, acc[mt], 0, 0, 0);
      }
    };

    float predp[4][4];
#pragma unroll
    for (int mt = 0; mt < 4; ++mt)
#pragma unroll
      for (int jj = 0; jj < 4; ++jj) predp[mt][jj] = 0.f;

    float predf[16];

    // epilogue with deferred-pred rank-1 correction:
    // s = acc + pred_prev[row]*W1[64][col];  S += w2 * rcp(1 + exp2(2L*s + 2L*b1))
    auto epi = [&](int nt, f32x4* acc) {
#pragma unroll
      for (int mt = 0; mt < 4; ++mt)
#pragma unroll
        for (int jj = 0; jj < 4; ++jj) {
          float sa = fmaf(TWO_L, acc[mt][jj], b1x[nt]);
          sa = fmaf(predf[mt * 4 + jj], w164L[nt], sa);
          float e  = __builtin_amdgcn_exp2f(sa);
          float rr = __builtin_amdgcn_rcpf(1.0f + e);
          predp[mt][jj] = fmaf(w2v[nt], rr, predp[mt][jj]);
        }
    };

    // ---- software-pipelined GEMM/epilogue: every epilogue has an
    //      independent MFMA group in flight on the matrix pipe ----
    f32x4 accA[4], accB[4];
    mfma_nt(0, accA);
    mfma_nt(1, accB);

    __builtin_amdgcn_sched_barrier(0);
    while (__hip_atomic_load(flagw, __ATOMIC_ACQUIRE, __HIP_MEMORY_SCOPE_WORKGROUP) !=
           (unsigned)t) {}
#pragma unroll
    for (int mt = 0; mt < 4; ++mt) {
      f16x4 pv4 = *(const f16x4*)(predf16 + mt * 16 + ((lane >> 4) << 2));
#pragma unroll
      for (int jj = 0; jj < 4; ++jj) predf[mt * 4 + jj] = (float)pv4[jj];
    }

    epi(0, accA); mfma_nt(2, accA);
    epi(1, accB); mfma_nt(3, accB);
    epi(2, accA); mfma_nt(4, accA);
    epi(3, accB); mfma_nt(5, accB);
    epi(4, accA); mfma_nt(6, accA);
    epi(5, accB); mfma_nt(7, accB);
    epi(6, accA);
    epi(7, accB);

    // wave reduce over the 16 col-lanes
#pragma unroll
    for (int mt = 0; mt < 4; ++mt)
#pragma unroll
      for (int jj = 0; jj < 4; ++jj) {
        float v = predp[mt][jj];
        v += __shfl_xor(v, 1); v += __shfl_xor(v, 2);
        v += __shfl_xor(v, 4); v += __shfl_xor(v, 8);
        if ((lane & 15) == 0)
          predbuf[wave * 64 + mt * 16 + ((lane >> 4) << 2) + jj] = v;
      }
    __syncthreads();  // [A] predbuf ready; X fully read for step t

    // wave 0: post own half-sum for pred_t (partner reads it at its step t+1)
    if (wave == 0) {
      float own = 0.f;
#pragma unroll
      for (int w = 0; w < NWAVES; ++w) own += predbuf[w * 64 + lane];
      contrib = Chalf - 2.0f * own;
      unsigned long long val =
          ((unsigned long long)(unsigned)(t + 1) << 32) |
          (unsigned long long)__builtin_bit_cast(unsigned, contrib);
      __hip_atomic_store(&mbox[((size_t)(b * 2 + par)) * 64 + lane], val,
                         __ATOMIC_RELAXED, __HIP_MEMORY_SCOPE_AGENT);
    }

    // ---- y shift into the other parity buffer (no cross-thread WAR),
    //      u_{t+1} write, u_{t+2} prefetch ----
    {
      int r3 = tid >> 3, j0 = (tid & 7) * 8;
      int sw3 = (r3 & 7) << 4;
      const char* ypar = smem + Y_OFF + par * 8192;
      char*       ynxt = smem + Y_OFF + (par ^ 1) * 8192;
      f16x8 chB = *(const f16x8*)(ypar + ((r3 * 128 + j0 * 2) ^ sw3));
      f16x8 nw;
      if (j0) {
        nw[0] = *(const f16*)(ypar + ((r3 * 128 + j0 * 2 - 2) ^ sw3));
        nw[1] = chB[0];
      } else {
        nw[0] = (f16)0.f;            // deferred slot for pred_t
        nw[1] = predf16[r3];         // logical old col 0 = pred_{t-1}
      }
#pragma unroll
      for (int i = 2; i < 8; ++i) nw[i] = chB[i - 1];
      *(f16x8*)(ynxt + ((r3 * 128 + j0 * 2) ^ sw3)) = nw;

      if (t + 1 < T_STEPS) {
        f16x8 pk;
        pk[0] = (f16)up0.x; pk[1] = (f16)up0.y; pk[2] = (f16)up0.z; pk[3] = (f16)up0.w;
        pk[4] = (f16)up1.x; pk[5] = (f16)up1.y; pk[6] = (f16)up1.z; pk[7] = (f16)up1.w;
        *(f16x8*)(smem + U_OFF + ((r3 * 128 + j0 * 2) ^ sw3)) = pk;
      }
      if (t + 2 < T_STEPS) {
        const float4* p =
            (const float4*)(u + ((size_t)(row0 + r3) * T_STEPS + t + 2) * 64 + j0);
        up0 = p[0]; up1 = p[1];
      }
    }
    __syncthreads();  // [C] X valid for step t+1
  }

  // flush the final prediction (t = 255)
  if (wave == 0) {
    const unsigned want = (unsigned)T_STEPS;
    unsigned long long pv;
    do {
      pv = __hip_atomic_load(&mbox[((size_t)(partner * 2 + 1)) * 64 + lane],
                             __ATOMIC_RELAXED, __HIP_MEMORY_SCOPE_AGENT);
    } while ((unsigned)(pv >> 32) != want);
    float pc = __builtin_bit_cast(float, (unsigned)(pv & 0xffffffffu));
    float ps = contrib + pc + b2v;
    if (half == 0) out[(size_t)(row0 + lane) * T_STEPS + (T_STEPS - 1)] = ps;
  }
}

extern "C" void kernel_launch(void* const* d_in, const int* in_sizes, int n_in,
                              void* d_out, int out_size, void* d_ws, size_t ws_size,
                              hipStream_t stream) {
  const float* u  = (const float*)d_in[0];
  const float* y0 = (const float*)d_in[1];
  const float* W1 = (const float*)d_in[2];
  const float* b1 = (const float*)d_in[3];
  const float* W2 = (const float*)d_in[4];
  const float* b2 = (const float*)d_in[5];

  f16* w1p = (f16*)d_ws;
  unsigned long long* mbox = (unsigned long long*)((char*)d_ws + MBOX_OFF);

  // mailboxes must be zero at every launch (stale tags from a previous replay
  // would alias tags of this launch)
  hipMemsetAsync((char*)d_ws + MBOX_OFF, 0, MBOX_BYTES, stream);

  prepack_w1<<<512, 64, 0, stream>>>(W1, w1p);

  rnn_fused<<<256, 512, 0, stream>>>(u, y0, w1p, W1, b1, W2, b2,
                                     (float*)d_out, mbox);
}